// Round 3
// baseline (160.549 us; speedup 1.0000x reference)
//
#include <hip/hip_runtime.h>
#include <hip/hip_bf16.h>
#include <stdint.h>
#include <string.h>

typedef unsigned short u16;
typedef unsigned int u32;
typedef __bf16 bf16x8 __attribute__((ext_vector_type(8)));
typedef float f32x4 __attribute__((ext_vector_type(4)));
typedef unsigned int u32x2v __attribute__((ext_vector_type(2)));

// Problem constants
#define NB 4
#define NC 64
#define NH 8
#define NL 2048
#define HC 512   // H*C

// Workspace layout (bytes).
#define XT_OFF  ((size_t)0)          // bf16 xT[b][l][c]            1 MB
#define WM_OFF  ((size_t)1 << 20)    // bf16 Wm[tns][d][o][c]       576 KB
#define PBM_OFF ((size_t)2 << 20)    // f32  pbm[tns][o]            6 KB
#define V_OFF   ((size_t)4 << 20)    // bf16 v[b][o][l]             8 MB
#define QT_OFF  ((size_t)12 << 20)   // bf16 qT[bh][l][c]           8 MB
#define KT_OFF  ((size_t)20 << 20)   // bf16 kT[bh][l][c]           8 MB

#define LP 68   // padded LDS row stride (u16); 136B = 34 words -> 2-bank row
                // rotation: 16-row fragment reads are 2-way (free per m136)

#if __has_builtin(__builtin_amdgcn_exp2f)
#define EXP2F __builtin_amdgcn_exp2f
#else
#define EXP2F exp2f
#endif

static __device__ __forceinline__ u16 f2bfu(float f) {
  union { float f; unsigned int i; } x; x.f = f;
  unsigned int i = x.i;
  return (u16)((i + 0x7fffu + ((i >> 16) & 1u)) >> 16);  // RTE, finite inputs
}
static __device__ __forceinline__ u32 pk2(float a, float b) {
  float2 f; f.x = a; f.y = b;
  __hip_bfloat162 h = __float22bfloat162_rn(f);   // packed cvt on gfx950
  u32 w; __builtin_memcpy(&w, &h, 4); return w;
}
static __device__ __forceinline__ bf16x8 ld_bf8(const u16* p) {
  bf16x8 v; __builtin_memcpy(&v, p, 16); return v;
}
static __device__ __forceinline__ bf16x8 frag_from4(u32 a, u32 b, u32 c, u32 d) {
  u32 t[4] = {a, b, c, d};
  bf16x8 v; __builtin_memcpy(&v, t, 16); return v;
}

// Quad exchange: source lane (q',l) word h of pair (X, Y) ->
// frag words Fa (elems +0..3 halves) and Fb (elems +4..7 halves).
// permlane32_swap(X,Y): A=(X0,X1,Y0,Y1) B=(X2,X3,Y2,Y3)  (quads)
// permlane16_swap(A,B): (X0,X2,Y0,Y2) , (X1,X3,Y1,Y3)
#define XCHG(X_, Y_, Fa_, Fb_)                                              \
  {                                                                         \
    u32x2v a_ = __builtin_amdgcn_permlane32_swap((X_), (Y_), false, false); \
    u32x2v b_ = __builtin_amdgcn_permlane16_swap(a_.x, a_.y, false, false); \
    Fa_ = b_.x; Fb_ = b_.y;                                                 \
  }

// ---------------------------------------------------------------------------
// Kernel P: fused prep. Block ranges:
//  [0,512)    init_out: out[b,c,l] = ub[c]
//  [512,902)  prep_w: merged conv weights + folded bias
//  [902,1030) prep_x: x[b][c][l] f32 -> xT[b][l][c] bf16
// ---------------------------------------------------------------------------
__global__ __launch_bounds__(256) void prep_all(
    const float* __restrict__ x,
    const float* __restrict__ qdw, const float* __restrict__ qdb,
    const float* __restrict__ qpw, const float* __restrict__ qpb,
    const float* __restrict__ kdw, const float* __restrict__ kdb,
    const float* __restrict__ kpw, const float* __restrict__ kpb,
    const float* __restrict__ vdw, const float* __restrict__ vdb,
    const float* __restrict__ vpw, const float* __restrict__ vpb,
    const float* __restrict__ ub,
    u16* __restrict__ Wm, float* __restrict__ pbm,
    u16* __restrict__ xT, float* __restrict__ out)
{
  __shared__ __align__(16) u16 T[64 * LP];
  int bx = blockIdx.x;
  int tid = threadIdx.x;

  if (bx < 512) {
    int i4 = bx * 256 + tid;     // float4 index
    int c = (i4 >> 9) & 63;
    float f = ub[c];
    float4 v = {f, f, f, f};
    ((float4*)out)[i4] = v;
    return;
  }
  if (bx < 902) {
    int idx = (bx - 512) * 256 + tid;
    if (idx < 98304) {
      int tns = idx >> 15, r = idx & 32767, o = r >> 6, c = r & 63;
      const float* dw = (tns == 0) ? qdw : (tns == 1) ? kdw : vdw;
      const float* pw = (tns == 0) ? qpw : (tns == 1) ? kpw : vpw;
      float s = (tns == 0) ? 0.35355339059327373f * 1.4426950408889634f
              : (tns == 1) ? 0.35355339059327373f : 1.0f;
      float w = pw[o * 64 + c] * s;
#pragma unroll
      for (int d = 0; d < 3; ++d)
        Wm[((size_t)(tns * 3 + d) * 512 + o) * 64 + c] = f2bfu(w * dw[c * 3 + d]);
    } else {
      int i = idx - 98304;
      int tns = i >> 9, o = i & 511;
      const float* db = (tns == 0) ? qdb : (tns == 1) ? kdb : vdb;
      const float* pw = (tns == 0) ? qpw : (tns == 1) ? kpw : vpw;
      const float* pb = (tns == 0) ? qpb : (tns == 1) ? kpb : vpb;
      float s = (tns == 0) ? 0.35355339059327373f * 1.4426950408889634f
              : (tns == 1) ? 0.35355339059327373f : 1.0f;
      float bias = pb[o];
      for (int c = 0; c < 64; ++c) bias += pw[o * 64 + c] * db[c];
      pbm[i] = bias * s;
    }
    return;
  }
  // prep_x
  {
    int b2 = bx - 902;
    int lt = b2 & 31, b = b2 >> 5;
    {
      int c = tid & 63, ls = (tid >> 6) * 16;
      const float4* g = (const float4*)(x + ((size_t)b * NC + c) * NL + lt * 64 + ls);
      u16 tmp[16];
#pragma unroll
      for (int j4 = 0; j4 < 4; ++j4) {
        float4 f = g[j4];
        tmp[j4*4+0] = f2bfu(f.x); tmp[j4*4+1] = f2bfu(f.y);
        tmp[j4*4+2] = f2bfu(f.z); tmp[j4*4+3] = f2bfu(f.w);
      }
#pragma unroll
      for (int j = 0; j < 16; ++j) T[(ls + j) * LP + c] = tmp[j];
    }
    __syncthreads();
    {
      int r = tid >> 2, cs = (tid & 3) * 16;
      uint4 a = *(const uint4*)&T[r * LP + cs];
      uint4 b3 = *(const uint4*)&T[r * LP + cs + 8];
      u16* o = xT + ((size_t)b * NL + lt * 64 + r) * 64 + cs;
      *(uint4*)o = a;
      *(uint4*)(o + 8) = b3;
    }
  }
}

// ---------------------------------------------------------------------------
// Kernel 1: qkv via MFMA, 4 l-tiles per block (weights staged once, XS
// double-buffered with register prefetch; 2 barriers/tile).
// grid = 4b * 3tns * 8och * 8 lgroups = 768 blocks; LDS 52.8 KB -> 3/CU.
// ---------------------------------------------------------------------------
__global__ __launch_bounds__(256) void qkv_gemm(
    const u16* __restrict__ xT, const u16* __restrict__ Wm,
    const float* __restrict__ pbm,
    u16* __restrict__ v, u16* __restrict__ qT, u16* __restrict__ kT)
{
  __shared__ __align__(16) u16 WS[3][64 * LP];   // WS[d][o][c]
  __shared__ __align__(16) u16 XS[2][66 * LP];   // XS[buf][r][c], r0 = l0-1
  __shared__ __align__(16) u16 OS[64 * LP];      // epilogue staging

  int bx = blockIdx.x;
  int lg  = bx & 7;
  int och = (bx >> 3) & 7;
  int tmp = bx >> 6;
  int tns = tmp % 3;
  int b   = tmp / 3;

  int tid = threadIdx.x;
  int wave = tid >> 6, lane = tid & 63, quad = lane >> 4, l16 = lane & 15;
  const u16* xg = xT + (size_t)b * NL * 64;

  // stage merged weights once (o-chunk slice, 3 d-slices)
  {
    const u16* wg = Wm + ((size_t)(tns * 3) * 512 + och * 64) * 64;
#pragma unroll
    for (int it = 0; it < 6; ++it) {
      int s = tid + it * 256;
      int d = s >> 9, r = s & 511;
      int o = r >> 3, c4 = r & 7;
      uint4 w = *(const uint4*)(wg + ((size_t)d * 512 + o) * 64 + c4 * 8);
      *(uint4*)&WS[d][o * LP + c4 * 8] = w;
    }
  }

  // XS prefetch helpers: 528 uint4 slots (66 rows x 8), <=3 per thread
  int xr0 = tid >> 3,          xc0 = (tid & 7) * 8;
  int xr1 = (tid + 256) >> 3,  xc1 = xc0;
  int xr2 = (tid + 512) >> 3,  xc2 = xc0;
  uint4 R0, R1, R2;
  uint4 Z = {0, 0, 0, 0};

#define LOAD_XS(tt)                                                         \
  {                                                                         \
    int base = (lg * 4 + (tt)) * 64 - 1;                                    \
    int g0 = base + xr0, g1 = base + xr1, g2 = base + xr2;                  \
    R0 = ((unsigned)g0 < NL) ? *(const uint4*)(xg + (size_t)g0 * 64 + xc0) : Z; \
    R1 = ((unsigned)g1 < NL) ? *(const uint4*)(xg + (size_t)g1 * 64 + xc1) : Z; \
    if (tid < 16)                                                           \
      R2 = ((unsigned)g2 < NL) ? *(const uint4*)(xg + (size_t)g2 * 64 + xc2) : Z; \
  }
#define STORE_XS(bf)                                                        \
  {                                                                         \
    *(uint4*)&XS[bf][xr0 * LP + xc0] = R0;                                  \
    *(uint4*)&XS[bf][xr1 * LP + xc1] = R1;                                  \
    if (tid < 16) *(uint4*)&XS[bf][xr2 * LP + xc2] = R2;                    \
  }

  LOAD_XS(0); STORE_XS(0);
  LOAD_XS(1);
  __syncthreads();

  // bias regs + v-path hoisted A fragments (tile-invariant)
  float bias4[4];
  bf16x8 aw[3][2];
  if (tns == 2) {
    const float* pbt = pbm + tns * 512 + och * 64 + wave * 16;
#pragma unroll
    for (int rr = 0; rr < 4; ++rr) bias4[rr] = pbt[quad * 4 + rr];
#pragma unroll
    for (int d = 0; d < 3; ++d)
#pragma unroll
      for (int kh = 0; kh < 2; ++kh)
        aw[d][kh] = ld_bf8(&WS[d][(wave * 16 + l16) * LP + kh * 32 + quad * 8]);
  } else {
    const float* pbt = pbm + tns * 512 + och * 64;
#pragma unroll
    for (int nt = 0; nt < 4; ++nt) bias4[nt] = pbt[nt * 16 + l16];
  }

  for (int t = 0; t < 4; ++t) {
    int cur = t & 1;
    f32x4 acc[4] = {{0,0,0,0},{0,0,0,0},{0,0,0,0},{0,0,0,0}};

    if (tns == 2) {
#pragma unroll
      for (int nt = 0; nt < 4; ++nt)
#pragma unroll
        for (int d = 0; d < 3; ++d)
#pragma unroll
          for (int kh = 0; kh < 2; ++kh) {
            bf16x8 bx8 = ld_bf8(&XS[cur][(nt * 16 + l16 + d) * LP + kh * 32 + quad * 8]);
            acc[nt] = __builtin_amdgcn_mfma_f32_16x16x32_bf16(aw[d][kh], bx8, acc[nt], 0, 0, 0);
          }
    } else {
      bf16x8 ax[3][2];
#pragma unroll
      for (int d = 0; d < 3; ++d)
#pragma unroll
        for (int kh = 0; kh < 2; ++kh)
          ax[d][kh] = ld_bf8(&XS[cur][(wave * 16 + l16 + d) * LP + kh * 32 + quad * 8]);
#pragma unroll
      for (int nt = 0; nt < 4; ++nt)
#pragma unroll
        for (int d = 0; d < 3; ++d)
#pragma unroll
          for (int kh = 0; kh < 2; ++kh) {
            bf16x8 bw = ld_bf8(&WS[d][(nt * 16 + l16) * LP + kh * 32 + quad * 8]);
            acc[nt] = __builtin_amdgcn_mfma_f32_16x16x32_bf16(ax[d][kh], bw, acc[nt], 0, 0, 0);
          }
    }

    if (t < 3) { STORE_XS((t + 1) & 1); if (t < 2) LOAD_XS(t + 2); }
    __syncthreads();   // XS[next] ready; OS from prev tile fully consumed

    if (tns == 2) {
      // rows = o, cols = l; bias by row
#pragma unroll
      for (int nt = 0; nt < 4; ++nt)
#pragma unroll
        for (int rr = 0; rr < 4; ++rr)
          OS[(wave * 16 + quad * 4 + rr) * LP + nt * 16 + l16] =
              f2bfu(acc[nt][rr] + bias4[rr]);
    } else {
      // rows = l, cols = o; bias by col
#pragma unroll
      for (int nt = 0; nt < 4; ++nt)
#pragma unroll
        for (int rr = 0; rr < 4; ++rr)
          OS[(wave * 16 + quad * 4 + rr) * LP + nt * 16 + l16] =
              f2bfu(acc[nt][rr] + bias4[nt]);
    }
    __syncthreads();

    // coalesced store: 64 rows x 128B, 2 uint4 per thread
    {
      int lt = lg * 4 + t;
      int r = tid >> 2, ck = (tid & 3) * 16;
      uint4 a = *(const uint4*)&OS[r * LP + ck];
      uint4 b2 = *(const uint4*)&OS[r * LP + ck + 8];
      u16* gp;
      if (tns == 2)
        gp = v + ((size_t)(b * HC + och * 64 + r)) * NL + lt * 64 + ck;
      else {
        u16* dst = (tns == 0) ? qT : kT;
        gp = dst + ((size_t)(b * 8 + och) * NL + lt * 64 + r) * 64 + ck;
      }
      *(uint4*)gp = a;
      *(uint4*)(gp + 8) = b2;
    }
  }
#undef LOAD_XS
#undef STORE_XS
}

// ---------------------------------------------------------------------------
// Kernel 2: flash attention + fused unify. 512 blocks = 32 bh * 16 q-tiles
// of 128. 512 threads = 8 waves = 4 query-groups x 2 KEY-HALVES.
// Each wave: 32 queries x 32 keys -> same 16 MFMA/iter but only 8
// ds_read_b128/iter (was 16): LDS pipe was the bottleneck (288 LDS
// wave-ops/CU-iter ~ 3456 cyc = 46 us of the 64 us kernel). Partial O per
// key-half; epilogue is linear in O so both halves run it and atomicAdd
// accumulates. l cross-reduced once via 1KB LDS. In-register P/OT
// transposes (permlane). ONE barrier per iteration. LDS 44.5 KB -> 2/CU.
// ---------------------------------------------------------------------------
__global__ __launch_bounds__(512, 4) void attn_kernel(
    const u16* __restrict__ qT, const u16* __restrict__ kT,
    const u16* __restrict__ vg, const float* __restrict__ uw,
    float* __restrict__ outg)
{
  __shared__ __align__(16) u16 Kt[2][64 * LP];  // Kt[buf][key][c]
  __shared__ __align__(16) u16 Vt[2][64 * LP];  // Vt[buf][c][key]
  __shared__ __align__(16) u16 UW[64 * LP];     // UW[c][c']
  __shared__ float LX[8][2][16];                // per-wave partial l

  int bx = blockIdx.x;
  int qt = bx & 15, bh = bx >> 4;
  int b = bh >> 3, h = bh & 7;
  int tid = threadIdx.x;
  int wave = tid >> 6, lane = tid & 63, quad = lane >> 4, l16 = lane & 15;
  int qs = wave >> 1, kb = wave & 1;   // query group (32q), key half (32k)

  const u16* Qh = qT + (size_t)bh * NL * 64;
  const u16* Kh = kT + (size_t)bh * NL * 64;
  const u16* Vh = vg + ((size_t)(b * HC + h * NC)) * NL;
  int q0 = qt * 128;

  int sr = tid >> 3, ss = (tid & 7) * 8;    // K staging: row, u16-col (1 uint4/thread)
  int vc = tid >> 3, vk = (tid & 7) * 8;    // V staging: c row, key seg

  // stage UW head slice as bf16: UW[c][c'] = uw[c*512 + h*64 + c']
  {
    int c = tid >> 3, g = (tid & 7) * 8;
    const float4* s = (const float4*)(uw + (size_t)c * HC + h * 64 + g);
    float4 w0 = s[0], w1 = s[1];
    u16* d = &UW[c * LP + g];
    d[0] = f2bfu(w0.x); d[1] = f2bfu(w0.y); d[2] = f2bfu(w0.z); d[3] = f2bfu(w0.w);
    d[4] = f2bfu(w1.x); d[5] = f2bfu(w1.y); d[6] = f2bfu(w1.z); d[7] = f2bfu(w1.w);
  }

  // K/V tile loads (regs) + buf0 fill, tile1 prefetch (1 uint4 each/thread)
  uint4 ka, va;
  {
    ka = *(const uint4*)(Kh + (size_t)sr * 64 + ss);
    va = *(const uint4*)(Vh + (size_t)vc * NL + vk);
    *(uint4*)&Kt[0][sr * LP + ss] = ka;
    *(uint4*)&Vt[0][vc * LP + vk] = va;
    ka = *(const uint4*)(Kh + (size_t)(64 + sr) * 64 + ss);
    va = *(const uint4*)(Vh + (size_t)vc * NL + 64 + vk);
  }

  // Q fragments for this wave's 32 queries, straight from global (no LDS)
  bf16x8 bq[2][2];
#pragma unroll
  for (int t = 0; t < 2; ++t)
#pragma unroll
    for (int kh = 0; kh < 2; ++kh)
      bq[t][kh] = ld_bf8(Qh + (size_t)(q0 + qs * 32 + t * 16 + l16) * 64 +
                         kh * 32 + quad * 8);

  __syncthreads();

  f32x4 o[2][4];
#pragma unroll
  for (int t = 0; t < 2; ++t)
#pragma unroll
    for (int ct = 0; ct < 4; ++ct) o[t][ct] = (f32x4){0, 0, 0, 0};
  float l_part[2] = {0.f, 0.f};

  for (int i = 0; i < 32; ++i) {
    int cur = i & 1;
    // this wave's key-half fragments: K rows kb*32.., V keys kb*32..
    bf16x8 ak[2][2], av[4];
#pragma unroll
    for (int j = 0; j < 2; ++j)
#pragma unroll
      for (int ch = 0; ch < 2; ++ch)
        ak[j][ch] = ld_bf8(&Kt[cur][(kb * 32 + j * 16 + l16) * LP + ch * 32 + quad * 8]);
#pragma unroll
    for (int ct = 0; ct < 4; ++ct)
      av[ct] = ld_bf8(&Vt[cur][(ct * 16 + l16) * LP + kb * 32 + quad * 8]);

#pragma unroll
    for (int t = 0; t < 2; ++t) {
      // S = K^T Q (rows=keys of this half, cols=queries), log2 domain
      f32x4 s0 = {0, 0, 0, 0}, s1 = {0, 0, 0, 0};
      s0 = __builtin_amdgcn_mfma_f32_16x16x32_bf16(ak[0][0], bq[t][0], s0, 0, 0, 0);
      s0 = __builtin_amdgcn_mfma_f32_16x16x32_bf16(ak[0][1], bq[t][1], s0, 0, 0, 0);
      s1 = __builtin_amdgcn_mfma_f32_16x16x32_bf16(ak[1][0], bq[t][0], s1, 0, 0, 0);
      s1 = __builtin_amdgcn_mfma_f32_16x16x32_bf16(ak[1][1], bq[t][1], s1, 0, 0, 0);
      // p = 2^s
      float p0 = EXP2F(s0[0]), p1 = EXP2F(s0[1]), p2 = EXP2F(s0[2]), p3 = EXP2F(s0[3]);
      float p4 = EXP2F(s1[0]), p5 = EXP2F(s1[1]), p6 = EXP2F(s1[2]), p7 = EXP2F(s1[3]);
      l_part[t] += ((p0 + p1) + (p2 + p3)) + ((p4 + p5) + (p6 + p7));
      u32 wA0 = pk2(p0, p1), wB0 = pk2(p2, p3);
      u32 wA1 = pk2(p4, p5), wB1 = pk2(p6, p7);
      // in-register transpose to PV B-fragment (32-key contraction)
      u32 F0, F1, F2, F3;
      XCHG(wA0, wA1, F0, F2);
      XCHG(wB0, wB1, F1, F3);
      bf16x8 bp = frag_from4(F0, F1, F2, F3);
#pragma unroll
      for (int ct = 0; ct < 4; ++ct)
        o[t][ct] = __builtin_amdgcn_mfma_f32_16x16x32_bf16(av[ct], bp, o[t][ct], 0, 0, 0);
    }

    if (i < 31) {
      int nxt = cur ^ 1;
      *(uint4*)&Kt[nxt][sr * LP + ss] = ka;
      *(uint4*)&Vt[nxt][vc * LP + vk] = va;
      if (i < 30) {
        int kt2 = (i + 2) * 64;
        ka = *(const uint4*)(Kh + (size_t)(kt2 + sr) * 64 + ss);
        va = *(const uint4*)(Vh + (size_t)vc * NL + kt2 + vk);
      }
    }
    __syncthreads();   // the ONLY barrier per iteration
  }

  // cross-wave l reduction (key halves) then epilogue per sub-tile
#pragma unroll
  for (int t = 0; t < 2; ++t) {
    float lp = l_part[t];
    lp += __shfl_xor(lp, 16);
    lp += __shfl_xor(lp, 32);
    l_part[t] = lp;                       // all lanes: partial l for query l16
  }
  if (quad == 0) {
    LX[wave][0][l16] = l_part[0];
    LX[wave][1][l16] = l_part[1];
  }
  __syncthreads();

  float* ob = outg + ((size_t)b * NC) * NL;
#pragma unroll
  for (int t = 0; t < 2; ++t) {
    float rinv = 1.0f / (LX[wave][t][l16] + LX[wave ^ 1][t][l16]);

    // pack normalized partial O (rows=c', cols=q), quad-exchange to B-frags
    u32 w01[4], w23[4];
#pragma unroll
    for (int ct = 0; ct < 4; ++ct) {
      w01[ct] = pk2(o[t][ct][0] * rinv, o[t][ct][1] * rinv);
      w23[ct] = pk2(o[t][ct][2] * rinv, o[t][ct][3] * rinv);
    }
    bf16x8 ot[2];
#pragma unroll
    for (int kh = 0; kh < 2; ++kh) {
      u32 F0, F1, F2, F3;
      XCHG(w01[2 * kh], w01[2 * kh + 1], F0, F2);
      XCHG(w23[2 * kh], w23[2 * kh + 1], F1, F3);
      ot[kh] = frag_from4(F0, F1, F2, F3);
    }

    int qcol = q0 + qs * 32 + t * 16 + l16;
#pragma unroll
    for (int mt = 0; mt < 4; ++mt) {
      f32x4 acc = {0, 0, 0, 0};
#pragma unroll
      for (int kh = 0; kh < 2; ++kh) {
        bf16x8 a = ld_bf8(&UW[(mt * 16 + l16) * LP + kh * 32 + quad * 8]);
        acc = __builtin_amdgcn_mfma_f32_16x16x32_bf16(a, ot[kh], acc, 0, 0, 0);
      }
#pragma unroll
      for (int rr = 0; rr < 4; ++rr) {
        int c = mt * 16 + quad * 4 + rr;
        atomicAdd(&ob[(size_t)c * NL + qcol], acc[rr]);
      }
    }
  }
}

// ---------------------------------------------------------------------------
extern "C" void kernel_launch(void* const* d_in, const int* in_sizes, int n_in,
                              void* d_out, int out_size, void* d_ws, size_t ws_size,
                              hipStream_t stream) {
  (void)in_sizes; (void)n_in; (void)out_size; (void)ws_size;
  const float* x   = (const float*)d_in[0];
  const float* qdw = (const float*)d_in[1];
  const float* qdb = (const float*)d_in[2];
  const float* qpw = (const float*)d_in[3];
  const float* qpb = (const float*)d_in[4];
  const float* kdw = (const float*)d_in[5];
  const float* kdb = (const float*)d_in[6];
  const float* kpw = (const float*)d_in[7];
  const float* kpb = (const float*)d_in[8];
  const float* vdw = (const float*)d_in[9];
  const float* vdb = (const float*)d_in[10];
  const float* vpw = (const float*)d_in[11];
  const float* vpb = (const float*)d_in[12];
  const float* uw  = (const float*)d_in[13];
  const float* ub  = (const float*)d_in[14];

  char* ws = (char*)d_ws;
  u16*   xT  = (u16*)(ws + XT_OFF);
  u16*   Wm  = (u16*)(ws + WM_OFF);
  float* pbm = (float*)(ws + PBM_OFF);
  u16*   v   = (u16*)(ws + V_OFF);
  u16*   qT  = (u16*)(ws + QT_OFF);
  u16*   kT  = (u16*)(ws + KT_OFF);
  float* out = (float*)d_out;

  prep_all<<<1030, 256, 0, stream>>>(
      x, qdw, qdb, qpw, qpb, kdw, kdb, kpw, kpb, vdw, vdb, vpw, vpb,
      ub, Wm, pbm, xT, out);
  qkv_gemm<<<768, 256, 0, stream>>>(xT, Wm, pbm, v, qT, kT);
  attn_kernel<<<512, 512, 0, stream>>>(qT, kT, v, uw, out);
}

// Round 4
// 158.151 us; speedup vs baseline: 1.0152x; 1.0152x over previous
//
#include <hip/hip_runtime.h>
#include <hip/hip_bf16.h>
#include <stdint.h>
#include <string.h>

typedef unsigned short u16;
typedef unsigned int u32;
typedef __bf16 bf16x8 __attribute__((ext_vector_type(8)));
typedef float f32x4 __attribute__((ext_vector_type(4)));
typedef unsigned int u32x2v __attribute__((ext_vector_type(2)));

// Problem constants
#define NB 4
#define NC 64
#define NH 8
#define NL 2048
#define HC 512   // H*C

// Workspace layout (bytes).
#define XT_OFF  ((size_t)0)          // bf16 xT[b][l][c]            1 MB
#define WM_OFF  ((size_t)1 << 20)    // bf16 Wm[tns][d][o][c]       576 KB
#define PBM_OFF ((size_t)2 << 20)    // f32  pbm[tns][o]            6 KB
#define V_OFF   ((size_t)4 << 20)    // bf16 v[b][o][l]             8 MB
#define QT_OFF  ((size_t)12 << 20)   // bf16 qT[bh][l][c]           8 MB
#define KT_OFF  ((size_t)20 << 20)   // bf16 kT[bh][l][c]           8 MB

#define LP 68   // padded LDS row stride (u16); 136B = 34 words -> 2-bank row
                // rotation: 16-row fragment reads are 2-way (free per m136)

#if __has_builtin(__builtin_amdgcn_exp2f)
#define EXP2F __builtin_amdgcn_exp2f
#else
#define EXP2F exp2f
#endif

static __device__ __forceinline__ u16 f2bfu(float f) {
  union { float f; unsigned int i; } x; x.f = f;
  unsigned int i = x.i;
  return (u16)((i + 0x7fffu + ((i >> 16) & 1u)) >> 16);  // RTE, finite inputs
}
static __device__ __forceinline__ u32 pk2(float a, float b) {
  float2 f; f.x = a; f.y = b;
  __hip_bfloat162 h = __float22bfloat162_rn(f);   // packed cvt on gfx950
  u32 w; __builtin_memcpy(&w, &h, 4); return w;
}
static __device__ __forceinline__ bf16x8 ld_bf8(const u16* p) {
  bf16x8 v; __builtin_memcpy(&v, p, 16); return v;
}
static __device__ __forceinline__ bf16x8 frag_from4(u32 a, u32 b, u32 c, u32 d) {
  u32 t[4] = {a, b, c, d};
  bf16x8 v; __builtin_memcpy(&v, t, 16); return v;
}

// Quad exchange: source lane (q',l) word h of pair (X, Y) ->
// frag words Fa (elems +0..3 halves) and Fb (elems +4..7 halves).
// permlane32_swap(X,Y): A=(X0,X1,Y0,Y1) B=(X2,X3,Y2,Y3)  (quads)
// permlane16_swap(A,B): (X0,X2,Y0,Y2) , (X1,X3,Y1,Y3)
#define XCHG(X_, Y_, Fa_, Fb_)                                              \
  {                                                                         \
    u32x2v a_ = __builtin_amdgcn_permlane32_swap((X_), (Y_), false, false); \
    u32x2v b_ = __builtin_amdgcn_permlane16_swap(a_.x, a_.y, false, false); \
    Fa_ = b_.x; Fb_ = b_.y;                                                 \
  }

// ---------------------------------------------------------------------------
// Kernel P: fused prep. Block ranges:
//  [0,512)    init_out: out[b,c,l] = ub[c]
//  [512,902)  prep_w: merged conv weights + folded bias
//  [902,1030) prep_x: x[b][c][l] f32 -> xT[b][l][c] bf16
// ---------------------------------------------------------------------------
__global__ __launch_bounds__(256) void prep_all(
    const float* __restrict__ x,
    const float* __restrict__ qdw, const float* __restrict__ qdb,
    const float* __restrict__ qpw, const float* __restrict__ qpb,
    const float* __restrict__ kdw, const float* __restrict__ kdb,
    const float* __restrict__ kpw, const float* __restrict__ kpb,
    const float* __restrict__ vdw, const float* __restrict__ vdb,
    const float* __restrict__ vpw, const float* __restrict__ vpb,
    const float* __restrict__ ub,
    u16* __restrict__ Wm, float* __restrict__ pbm,
    u16* __restrict__ xT, float* __restrict__ out)
{
  __shared__ __align__(16) u16 T[64 * LP];
  int bx = blockIdx.x;
  int tid = threadIdx.x;

  if (bx < 512) {
    int i4 = bx * 256 + tid;     // float4 index
    int c = (i4 >> 9) & 63;
    float f = ub[c];
    float4 v = {f, f, f, f};
    ((float4*)out)[i4] = v;
    return;
  }
  if (bx < 902) {
    int idx = (bx - 512) * 256 + tid;
    if (idx < 98304) {
      int tns = idx >> 15, r = idx & 32767, o = r >> 6, c = r & 63;
      const float* dw = (tns == 0) ? qdw : (tns == 1) ? kdw : vdw;
      const float* pw = (tns == 0) ? qpw : (tns == 1) ? kpw : vpw;
      float s = (tns == 0) ? 0.35355339059327373f * 1.4426950408889634f
              : (tns == 1) ? 0.35355339059327373f : 1.0f;
      float w = pw[o * 64 + c] * s;
#pragma unroll
      for (int d = 0; d < 3; ++d)
        Wm[((size_t)(tns * 3 + d) * 512 + o) * 64 + c] = f2bfu(w * dw[c * 3 + d]);
    } else {
      int i = idx - 98304;
      int tns = i >> 9, o = i & 511;
      const float* db = (tns == 0) ? qdb : (tns == 1) ? kdb : vdb;
      const float* pw = (tns == 0) ? qpw : (tns == 1) ? kpw : vpw;
      const float* pb = (tns == 0) ? qpb : (tns == 1) ? kpb : vpb;
      float s = (tns == 0) ? 0.35355339059327373f * 1.4426950408889634f
              : (tns == 1) ? 0.35355339059327373f : 1.0f;
      float bias = pb[o];
      for (int c = 0; c < 64; ++c) bias += pw[o * 64 + c] * db[c];
      pbm[i] = bias * s;
    }
    return;
  }
  // prep_x
  {
    int b2 = bx - 902;
    int lt = b2 & 31, b = b2 >> 5;
    {
      int c = tid & 63, ls = (tid >> 6) * 16;
      const float4* g = (const float4*)(x + ((size_t)b * NC + c) * NL + lt * 64 + ls);
      u16 tmp[16];
#pragma unroll
      for (int j4 = 0; j4 < 4; ++j4) {
        float4 f = g[j4];
        tmp[j4*4+0] = f2bfu(f.x); tmp[j4*4+1] = f2bfu(f.y);
        tmp[j4*4+2] = f2bfu(f.z); tmp[j4*4+3] = f2bfu(f.w);
      }
#pragma unroll
      for (int j = 0; j < 16; ++j) T[(ls + j) * LP + c] = tmp[j];
    }
    __syncthreads();
    {
      int r = tid >> 2, cs = (tid & 3) * 16;
      uint4 a = *(const uint4*)&T[r * LP + cs];
      uint4 b3 = *(const uint4*)&T[r * LP + cs + 8];
      u16* o = xT + ((size_t)b * NL + lt * 64 + r) * 64 + cs;
      *(uint4*)o = a;
      *(uint4*)(o + 8) = b3;
    }
  }
}

// ---------------------------------------------------------------------------
// Kernel 1: qkv via MFMA, 4 l-tiles per block (weights staged once, XS
// double-buffered with register prefetch; 2 barriers/tile).
// grid = 4b * 3tns * 8och * 8 lgroups = 768 blocks; LDS 52.8 KB -> 3/CU.
// ---------------------------------------------------------------------------
__global__ __launch_bounds__(256) void qkv_gemm(
    const u16* __restrict__ xT, const u16* __restrict__ Wm,
    const float* __restrict__ pbm,
    u16* __restrict__ v, u16* __restrict__ qT, u16* __restrict__ kT)
{
  __shared__ __align__(16) u16 WS[3][64 * LP];   // WS[d][o][c]
  __shared__ __align__(16) u16 XS[2][66 * LP];   // XS[buf][r][c], r0 = l0-1
  __shared__ __align__(16) u16 OS[64 * LP];      // epilogue staging

  int bx = blockIdx.x;
  int lg  = bx & 7;
  int och = (bx >> 3) & 7;
  int tmp = bx >> 6;
  int tns = tmp % 3;
  int b   = tmp / 3;

  int tid = threadIdx.x;
  int wave = tid >> 6, lane = tid & 63, quad = lane >> 4, l16 = lane & 15;
  const u16* xg = xT + (size_t)b * NL * 64;

  // stage merged weights once (o-chunk slice, 3 d-slices)
  {
    const u16* wg = Wm + ((size_t)(tns * 3) * 512 + och * 64) * 64;
#pragma unroll
    for (int it = 0; it < 6; ++it) {
      int s = tid + it * 256;
      int d = s >> 9, r = s & 511;
      int o = r >> 3, c4 = r & 7;
      uint4 w = *(const uint4*)(wg + ((size_t)d * 512 + o) * 64 + c4 * 8);
      *(uint4*)&WS[d][o * LP + c4 * 8] = w;
    }
  }

  // XS prefetch helpers: 528 uint4 slots (66 rows x 8), <=3 per thread
  int xr0 = tid >> 3,          xc0 = (tid & 7) * 8;
  int xr1 = (tid + 256) >> 3,  xc1 = xc0;
  int xr2 = (tid + 512) >> 3,  xc2 = xc0;
  uint4 R0, R1, R2;
  uint4 Z = {0, 0, 0, 0};

#define LOAD_XS(tt)                                                         \
  {                                                                         \
    int base = (lg * 4 + (tt)) * 64 - 1;                                    \
    int g0 = base + xr0, g1 = base + xr1, g2 = base + xr2;                  \
    R0 = ((unsigned)g0 < NL) ? *(const uint4*)(xg + (size_t)g0 * 64 + xc0) : Z; \
    R1 = ((unsigned)g1 < NL) ? *(const uint4*)(xg + (size_t)g1 * 64 + xc1) : Z; \
    if (tid < 16)                                                           \
      R2 = ((unsigned)g2 < NL) ? *(const uint4*)(xg + (size_t)g2 * 64 + xc2) : Z; \
  }
#define STORE_XS(bf)                                                        \
  {                                                                         \
    *(uint4*)&XS[bf][xr0 * LP + xc0] = R0;                                  \
    *(uint4*)&XS[bf][xr1 * LP + xc1] = R1;                                  \
    if (tid < 16) *(uint4*)&XS[bf][xr2 * LP + xc2] = R2;                    \
  }

  LOAD_XS(0); STORE_XS(0);
  LOAD_XS(1);
  __syncthreads();

  // bias regs + v-path hoisted A fragments (tile-invariant)
  float bias4[4];
  bf16x8 aw[3][2];
  if (tns == 2) {
    const float* pbt = pbm + tns * 512 + och * 64 + wave * 16;
#pragma unroll
    for (int rr = 0; rr < 4; ++rr) bias4[rr] = pbt[quad * 4 + rr];
#pragma unroll
    for (int d = 0; d < 3; ++d)
#pragma unroll
      for (int kh = 0; kh < 2; ++kh)
        aw[d][kh] = ld_bf8(&WS[d][(wave * 16 + l16) * LP + kh * 32 + quad * 8]);
  } else {
    const float* pbt = pbm + tns * 512 + och * 64;
#pragma unroll
    for (int nt = 0; nt < 4; ++nt) bias4[nt] = pbt[nt * 16 + l16];
  }

  for (int t = 0; t < 4; ++t) {
    int cur = t & 1;
    f32x4 acc[4] = {{0,0,0,0},{0,0,0,0},{0,0,0,0},{0,0,0,0}};

    if (tns == 2) {
#pragma unroll
      for (int nt = 0; nt < 4; ++nt)
#pragma unroll
        for (int d = 0; d < 3; ++d)
#pragma unroll
          for (int kh = 0; kh < 2; ++kh) {
            bf16x8 bx8 = ld_bf8(&XS[cur][(nt * 16 + l16 + d) * LP + kh * 32 + quad * 8]);
            acc[nt] = __builtin_amdgcn_mfma_f32_16x16x32_bf16(aw[d][kh], bx8, acc[nt], 0, 0, 0);
          }
    } else {
      bf16x8 ax[3][2];
#pragma unroll
      for (int d = 0; d < 3; ++d)
#pragma unroll
        for (int kh = 0; kh < 2; ++kh)
          ax[d][kh] = ld_bf8(&XS[cur][(wave * 16 + l16 + d) * LP + kh * 32 + quad * 8]);
#pragma unroll
      for (int nt = 0; nt < 4; ++nt)
#pragma unroll
        for (int d = 0; d < 3; ++d)
#pragma unroll
          for (int kh = 0; kh < 2; ++kh) {
            bf16x8 bw = ld_bf8(&WS[d][(nt * 16 + l16) * LP + kh * 32 + quad * 8]);
            acc[nt] = __builtin_amdgcn_mfma_f32_16x16x32_bf16(ax[d][kh], bw, acc[nt], 0, 0, 0);
          }
    }

    if (t < 3) { STORE_XS((t + 1) & 1); if (t < 2) LOAD_XS(t + 2); }
    __syncthreads();   // XS[next] ready; OS from prev tile fully consumed

    if (tns == 2) {
      // rows = o, cols = l; bias by row
#pragma unroll
      for (int nt = 0; nt < 4; ++nt)
#pragma unroll
        for (int rr = 0; rr < 4; ++rr)
          OS[(wave * 16 + quad * 4 + rr) * LP + nt * 16 + l16] =
              f2bfu(acc[nt][rr] + bias4[rr]);
    } else {
      // rows = l, cols = o; bias by col
#pragma unroll
      for (int nt = 0; nt < 4; ++nt)
#pragma unroll
        for (int rr = 0; rr < 4; ++rr)
          OS[(wave * 16 + quad * 4 + rr) * LP + nt * 16 + l16] =
              f2bfu(acc[nt][rr] + bias4[nt]);
    }
    __syncthreads();

    // coalesced store: 64 rows x 128B, 2 uint4 per thread
    {
      int lt = lg * 4 + t;
      int r = tid >> 2, ck = (tid & 3) * 16;
      uint4 a = *(const uint4*)&OS[r * LP + ck];
      uint4 b2 = *(const uint4*)&OS[r * LP + ck + 8];
      u16* gp;
      if (tns == 2)
        gp = v + ((size_t)(b * HC + och * 64 + r)) * NL + lt * 64 + ck;
      else {
        u16* dst = (tns == 0) ? qT : kT;
        gp = dst + ((size_t)(b * 8 + och) * NL + lt * 64 + r) * 64 + ck;
      }
      *(uint4*)gp = a;
      *(uint4*)(gp + 8) = b2;
    }
  }
#undef LOAD_XS
#undef STORE_XS
}

// ---------------------------------------------------------------------------
// Kernel 2: flash attention + fused unify. 1024 blocks = 32 bh * 32 q-tiles
// of 64. 256 threads = 4 waves * 16 queries * 64 keys/iter. LDS 25.5 KB ->
// up to 6 blocks/CU co-resident; avg 4 blocks/CU = 16 waves/CU with FOUR
// independent barrier groups per SIMD (the 512-thread version had two;
// stalls, not any pipe, dominate). K/V single-buffered in LDS; pipeline via
// registers: compute(i) overlaps in-flight gload(i+1); after the compute
// barrier, ds_write(i+1) + issue gload(i+2). l-sum via ones-fragment MFMA
// (replaces 16 VALU adds/iter + epilogue shuffles). In-register P/OT
// transposes (permlane). No setprio.
// ---------------------------------------------------------------------------
__global__ __launch_bounds__(256, 4) void attn_kernel(
    const u16* __restrict__ qT, const u16* __restrict__ kT,
    const u16* __restrict__ vg, const float* __restrict__ uw,
    float* __restrict__ outg)
{
  __shared__ __align__(16) u16 Kt[64 * LP];  // Kt[key][c]
  __shared__ __align__(16) u16 Vt[64 * LP];  // Vt[c][key]
  __shared__ __align__(16) u16 UW[64 * LP];  // UW[c][c']

  int bx = blockIdx.x;
  int qt = bx & 31, bh = bx >> 5;
  int b = bh >> 3, h = bh & 7;
  int tid = threadIdx.x;
  int wave = tid >> 6, lane = tid & 63, quad = lane >> 4, l16 = lane & 15;

  const u16* Qh = qT + (size_t)bh * NL * 64;
  const u16* Kh = kT + (size_t)bh * NL * 64;
  const u16* Vh = vg + ((size_t)(b * HC + h * NC)) * NL;
  int q0 = qt * 64;

  int sr = tid >> 2, ss = (tid & 3) * 16;   // K staging: row, u16-col (2 uint4/thread)
  int vc = tid >> 2, vk = (tid & 3) * 16;   // V staging: c row, key seg

  // stage UW head slice as bf16: UW[c][c'] = uw[c*512 + h*64 + c']
  {
    int c = tid >> 2, g = (tid & 3) * 16;
    const float4* s = (const float4*)(uw + (size_t)c * HC + h * 64 + g);
#pragma unroll
    for (int j = 0; j < 4; ++j) {
      float4 w = s[j];
      u16* d = &UW[c * LP + g + j * 4];
      d[0] = f2bfu(w.x); d[1] = f2bfu(w.y); d[2] = f2bfu(w.z); d[3] = f2bfu(w.w);
    }
  }

  // tile0 -> LDS; tile1 -> regs (in flight across first compute)
  uint4 ka, kb, va, vb;
  {
    const u16* ks = Kh + (size_t)sr * 64 + ss;
    ka = *(const uint4*)ks; kb = *(const uint4*)(ks + 8);
    const u16* vs = Vh + (size_t)vc * NL + vk;
    va = *(const uint4*)vs; vb = *(const uint4*)(vs + 8);
    *(uint4*)&Kt[sr * LP + ss] = ka;
    *(uint4*)&Kt[sr * LP + ss + 8] = kb;
    *(uint4*)&Vt[vc * LP + vk] = va;
    *(uint4*)&Vt[vc * LP + vk + 8] = vb;
    const u16* ks1 = Kh + (size_t)(64 + sr) * 64 + ss;
    ka = *(const uint4*)ks1; kb = *(const uint4*)(ks1 + 8);
    const u16* vs1 = Vh + (size_t)vc * NL + 64 + vk;
    va = *(const uint4*)vs1; vb = *(const uint4*)(vs1 + 8);
  }

  // Q fragments for this wave's 16 queries, straight from global (no LDS)
  bf16x8 bq[2];
#pragma unroll
  for (int kh = 0; kh < 2; ++kh)
    bq[kh] = ld_bf8(Qh + (size_t)(q0 + wave * 16 + l16) * 64 + kh * 32 + quad * 8);

  // all-ones A fragment for MFMA l-sum (column sums of P)
  bf16x8 ones = frag_from4(0x3F803F80u, 0x3F803F80u, 0x3F803F80u, 0x3F803F80u);

  __syncthreads();

  f32x4 o[4];
#pragma unroll
  for (int ct = 0; ct < 4; ++ct) o[ct] = (f32x4){0, 0, 0, 0};
  f32x4 lacc = {0, 0, 0, 0};

  for (int i = 0; i < 32; ++i) {
    // K and V fragments (full 64-key tile per wave)
    bf16x8 ak[4][2], av[4][2];
#pragma unroll
    for (int j = 0; j < 4; ++j)
#pragma unroll
      for (int kh = 0; kh < 2; ++kh) {
        ak[j][kh] = ld_bf8(&Kt[(j * 16 + l16) * LP + kh * 32 + quad * 8]);
        av[j][kh] = ld_bf8(&Vt[(j * 16 + l16) * LP + kh * 32 + quad * 8]);
      }

    // S = K^T Q (rows=keys, cols=queries), log2 domain
    f32x4 s[4];
#pragma unroll
    for (int ktl = 0; ktl < 4; ++ktl) {
      f32x4 z = {0, 0, 0, 0};
      z = __builtin_amdgcn_mfma_f32_16x16x32_bf16(ak[ktl][0], bq[0], z, 0, 0, 0);
      z = __builtin_amdgcn_mfma_f32_16x16x32_bf16(ak[ktl][1], bq[1], z, 0, 0, 0);
      s[ktl] = z;
    }
    // p = 2^s; pack to bf16 pairs per ktl
    u32 w01[4], w23[4];
#pragma unroll
    for (int ktl = 0; ktl < 4; ++ktl) {
      float p0 = EXP2F(s[ktl][0]);
      float p1 = EXP2F(s[ktl][1]);
      float p2 = EXP2F(s[ktl][2]);
      float p3 = EXP2F(s[ktl][3]);
      w01[ktl] = pk2(p0, p1);
      w23[ktl] = pk2(p2, p3);
    }
    // in-register transpose to PV B-fragments; O += V*P; l += colsum(P)
#pragma unroll
    for (int kh = 0; kh < 2; ++kh) {
      u32 F0, F1, F2, F3;
      XCHG(w01[2 * kh], w01[2 * kh + 1], F0, F2);
      XCHG(w23[2 * kh], w23[2 * kh + 1], F1, F3);
      bf16x8 bp = frag_from4(F0, F1, F2, F3);
      lacc = __builtin_amdgcn_mfma_f32_16x16x32_bf16(ones, bp, lacc, 0, 0, 0);
#pragma unroll
      for (int ct = 0; ct < 4; ++ct)
        o[ct] = __builtin_amdgcn_mfma_f32_16x16x32_bf16(av[ct][kh], bp, o[ct], 0, 0, 0);
    }

    __syncthreads();   // all waves done reading tile i
    if (i < 31) {
      *(uint4*)&Kt[sr * LP + ss] = ka;
      *(uint4*)&Kt[sr * LP + ss + 8] = kb;
      *(uint4*)&Vt[vc * LP + vk] = va;
      *(uint4*)&Vt[vc * LP + vk + 8] = vb;
      if (i < 30) {
        int kt2 = (i + 2) * 64;
        const u16* ks = Kh + (size_t)(kt2 + sr) * 64 + ss;
        ka = *(const uint4*)ks; kb = *(const uint4*)(ks + 8);
        const u16* vs = Vh + (size_t)vc * NL + kt2 + vk;
        va = *(const uint4*)vs; vb = *(const uint4*)(vs + 8);
      }
    }
    __syncthreads();   // tile i+1 visible
  }

  // epilogue: lacc holds l[q=l16] replicated across rows (ones-MFMA)
  float* ob = outg + ((size_t)b * NC) * NL;
  {
    float rinv = 1.0f / lacc[0];

    // pack normalized O (rows=c', cols=q) then quad-exchange to B-fragments
    u32 w01[4], w23[4];
#pragma unroll
    for (int ct = 0; ct < 4; ++ct) {
      w01[ct] = pk2(o[ct][0] * rinv, o[ct][1] * rinv);
      w23[ct] = pk2(o[ct][2] * rinv, o[ct][3] * rinv);
    }
    bf16x8 ot[2];
#pragma unroll
    for (int kh = 0; kh < 2; ++kh) {
      u32 F0, F1, F2, F3;
      XCHG(w01[2 * kh], w01[2 * kh + 1], F0, F2);
      XCHG(w23[2 * kh], w23[2 * kh + 1], F1, F3);
      ot[kh] = frag_from4(F0, F1, F2, F3);
    }

    int qcol = q0 + wave * 16 + l16;
#pragma unroll
    for (int mt = 0; mt < 4; ++mt) {
      f32x4 acc = {0, 0, 0, 0};
#pragma unroll
      for (int kh = 0; kh < 2; ++kh) {
        bf16x8 a = ld_bf8(&UW[(mt * 16 + l16) * LP + kh * 32 + quad * 8]);
        acc = __builtin_amdgcn_mfma_f32_16x16x32_bf16(a, ot[kh], acc, 0, 0, 0);
      }
#pragma unroll
      for (int rr = 0; rr < 4; ++rr) {
        int c = mt * 16 + quad * 4 + rr;
        atomicAdd(&ob[(size_t)c * NL + qcol], acc[rr]);
      }
    }
  }
}

// ---------------------------------------------------------------------------
extern "C" void kernel_launch(void* const* d_in, const int* in_sizes, int n_in,
                              void* d_out, int out_size, void* d_ws, size_t ws_size,
                              hipStream_t stream) {
  (void)in_sizes; (void)n_in; (void)out_size; (void)ws_size;
  const float* x   = (const float*)d_in[0];
  const float* qdw = (const float*)d_in[1];
  const float* qdb = (const float*)d_in[2];
  const float* qpw = (const float*)d_in[3];
  const float* qpb = (const float*)d_in[4];
  const float* kdw = (const float*)d_in[5];
  const float* kdb = (const float*)d_in[6];
  const float* kpw = (const float*)d_in[7];
  const float* kpb = (const float*)d_in[8];
  const float* vdw = (const float*)d_in[9];
  const float* vdb = (const float*)d_in[10];
  const float* vpw = (const float*)d_in[11];
  const float* vpb = (const float*)d_in[12];
  const float* uw  = (const float*)d_in[13];
  const float* ub  = (const float*)d_in[14];

  char* ws = (char*)d_ws;
  u16*   xT  = (u16*)(ws + XT_OFF);
  u16*   Wm  = (u16*)(ws + WM_OFF);
  float* pbm = (float*)(ws + PBM_OFF);
  u16*   v   = (u16*)(ws + V_OFF);
  u16*   qT  = (u16*)(ws + QT_OFF);
  u16*   kT  = (u16*)(ws + KT_OFF);
  float* out = (float*)d_out;

  prep_all<<<1030, 256, 0, stream>>>(
      x, qdw, qdb, qpw, qpb, kdw, kdb, kpw, kpb, vdw, vdb, vpw, vpb,
      ub, Wm, pbm, xT, out);
  qkv_gemm<<<768, 256, 0, stream>>>(xT, Wm, pbm, v, qT, kT);
  attn_kernel<<<1024, 256, 0, stream>>>(qT, kT, v, uw, out);
}

// Round 5
// 153.436 us; speedup vs baseline: 1.0464x; 1.0307x over previous
//
#include <hip/hip_runtime.h>
#include <hip/hip_bf16.h>
#include <stdint.h>
#include <string.h>

typedef unsigned short u16;
typedef unsigned int u32;
typedef __bf16 bf16x8 __attribute__((ext_vector_type(8)));
typedef float f32x4 __attribute__((ext_vector_type(4)));
typedef unsigned int u32x2v __attribute__((ext_vector_type(2)));

// Problem constants
#define NB 4
#define NC 64
#define NH 8
#define NL 2048
#define HC 512   // H*C

// Workspace layout (bytes).
#define XT_OFF  ((size_t)0)          // bf16 xT[b][l][c]            1 MB
#define WM_OFF  ((size_t)1 << 20)    // bf16 Wm[tns][d][o][c]       576 KB
#define PBM_OFF ((size_t)2 << 20)    // f32  pbm[tns][o]            6 KB
#define V_OFF   ((size_t)4 << 20)    // bf16 v[b][o][l]             8 MB
#define QT_OFF  ((size_t)12 << 20)   // bf16 qT[bh][l][c]           8 MB
#define KT_OFF  ((size_t)20 << 20)   // bf16 kT[bh][l][c]           8 MB

#define LP 68   // padded LDS row stride (u16); 136B = 34 words -> 2-bank row
                // rotation: 16-row fragment reads are 2-way (free per m136)

#if __has_builtin(__builtin_amdgcn_exp2f)
#define EXP2F __builtin_amdgcn_exp2f
#else
#define EXP2F exp2f
#endif

static __device__ __forceinline__ u16 f2bfu(float f) {
  union { float f; unsigned int i; } x; x.f = f;
  unsigned int i = x.i;
  return (u16)((i + 0x7fffu + ((i >> 16) & 1u)) >> 16);  // RTE, finite inputs
}
static __device__ __forceinline__ u32 pk2(float a, float b) {
  float2 f; f.x = a; f.y = b;
  __hip_bfloat162 h = __float22bfloat162_rn(f);   // packed cvt on gfx950
  u32 w; __builtin_memcpy(&w, &h, 4); return w;
}
static __device__ __forceinline__ bf16x8 ld_bf8(const u16* p) {
  bf16x8 v; __builtin_memcpy(&v, p, 16); return v;
}
static __device__ __forceinline__ bf16x8 frag_from4(u32 a, u32 b, u32 c, u32 d) {
  u32 t[4] = {a, b, c, d};
  bf16x8 v; __builtin_memcpy(&v, t, 16); return v;
}

// Quad exchange: source lane (q',l) word h of pair (X, Y) ->
// frag words Fa (elems +0..3 halves) and Fb (elems +4..7 halves).
// permlane32_swap(X,Y): A=(X0,X1,Y0,Y1) B=(X2,X3,Y2,Y3)  (quads)
// permlane16_swap(A,B): (X0,X2,Y0,Y2) , (X1,X3,Y1,Y3)
#define XCHG(X_, Y_, Fa_, Fb_)                                              \
  {                                                                         \
    u32x2v a_ = __builtin_amdgcn_permlane32_swap((X_), (Y_), false, false); \
    u32x2v b_ = __builtin_amdgcn_permlane16_swap(a_.x, a_.y, false, false); \
    Fa_ = b_.x; Fb_ = b_.y;                                                 \
  }

// ---------------------------------------------------------------------------
// Kernel P: fused prep. Block ranges:
//  [0,512)    init_out: out[b,c,l] = ub[c]
//  [512,902)  prep_w: merged conv weights + folded bias
//  [902,1030) prep_x: x[b][c][l] f32 -> xT[b][l][c] bf16
// ---------------------------------------------------------------------------
__global__ __launch_bounds__(256) void prep_all(
    const float* __restrict__ x,
    const float* __restrict__ qdw, const float* __restrict__ qdb,
    const float* __restrict__ qpw, const float* __restrict__ qpb,
    const float* __restrict__ kdw, const float* __restrict__ kdb,
    const float* __restrict__ kpw, const float* __restrict__ kpb,
    const float* __restrict__ vdw, const float* __restrict__ vdb,
    const float* __restrict__ vpw, const float* __restrict__ vpb,
    const float* __restrict__ ub,
    u16* __restrict__ Wm, float* __restrict__ pbm,
    u16* __restrict__ xT, float* __restrict__ out)
{
  __shared__ __align__(16) u16 T[64 * LP];
  int bx = blockIdx.x;
  int tid = threadIdx.x;

  if (bx < 512) {
    int i4 = bx * 256 + tid;     // float4 index
    int c = (i4 >> 9) & 63;
    float f = ub[c];
    float4 v = {f, f, f, f};
    ((float4*)out)[i4] = v;
    return;
  }
  if (bx < 902) {
    int idx = (bx - 512) * 256 + tid;
    if (idx < 98304) {
      int tns = idx >> 15, r = idx & 32767, o = r >> 6, c = r & 63;
      const float* dw = (tns == 0) ? qdw : (tns == 1) ? kdw : vdw;
      const float* pw = (tns == 0) ? qpw : (tns == 1) ? kpw : vpw;
      float s = (tns == 0) ? 0.35355339059327373f * 1.4426950408889634f
              : (tns == 1) ? 0.35355339059327373f : 1.0f;
      float w = pw[o * 64 + c] * s;
#pragma unroll
      for (int d = 0; d < 3; ++d)
        Wm[((size_t)(tns * 3 + d) * 512 + o) * 64 + c] = f2bfu(w * dw[c * 3 + d]);
    } else {
      int i = idx - 98304;
      int tns = i >> 9, o = i & 511;
      const float* db = (tns == 0) ? qdb : (tns == 1) ? kdb : vdb;
      const float* pw = (tns == 0) ? qpw : (tns == 1) ? kpw : vpw;
      const float* pb = (tns == 0) ? qpb : (tns == 1) ? kpb : vpb;
      float s = (tns == 0) ? 0.35355339059327373f * 1.4426950408889634f
              : (tns == 1) ? 0.35355339059327373f : 1.0f;
      float bias = pb[o];
      for (int c = 0; c < 64; ++c) bias += pw[o * 64 + c] * db[c];
      pbm[i] = bias * s;
    }
    return;
  }
  // prep_x
  {
    int b2 = bx - 902;
    int lt = b2 & 31, b = b2 >> 5;
    {
      int c = tid & 63, ls = (tid >> 6) * 16;
      const float4* g = (const float4*)(x + ((size_t)b * NC + c) * NL + lt * 64 + ls);
      u16 tmp[16];
#pragma unroll
      for (int j4 = 0; j4 < 4; ++j4) {
        float4 f = g[j4];
        tmp[j4*4+0] = f2bfu(f.x); tmp[j4*4+1] = f2bfu(f.y);
        tmp[j4*4+2] = f2bfu(f.z); tmp[j4*4+3] = f2bfu(f.w);
      }
#pragma unroll
      for (int j = 0; j < 16; ++j) T[(ls + j) * LP + c] = tmp[j];
    }
    __syncthreads();
    {
      int r = tid >> 2, cs = (tid & 3) * 16;
      uint4 a = *(const uint4*)&T[r * LP + cs];
      uint4 b3 = *(const uint4*)&T[r * LP + cs + 8];
      u16* o = xT + ((size_t)b * NL + lt * 64 + r) * 64 + cs;
      *(uint4*)o = a;
      *(uint4*)(o + 8) = b3;
    }
  }
}

// ---------------------------------------------------------------------------
// Kernel 1: qkv via MFMA, 4 l-tiles per block (weights staged once, XS
// double-buffered with register prefetch). ONE barrier per tile: the OS
// epilogue staging is now WAVE-PRIVATE (each wave writes rows wave*16..+15
// and reads back its own stripe), so the C-store needs only lgkmcnt(0),
// not a block barrier. grid = 768 blocks; LDS 52.8 KB -> 3/CU.
// ---------------------------------------------------------------------------
__global__ __launch_bounds__(256) void qkv_gemm(
    const u16* __restrict__ xT, const u16* __restrict__ Wm,
    const float* __restrict__ pbm,
    u16* __restrict__ v, u16* __restrict__ qT, u16* __restrict__ kT)
{
  __shared__ __align__(16) u16 WS[3][64 * LP];   // WS[d][o][c]
  __shared__ __align__(16) u16 XS[2][66 * LP];   // XS[buf][r][c], r0 = l0-1
  __shared__ __align__(16) u16 OS[64 * LP];      // epilogue staging (wave-private stripes)

  int bx = blockIdx.x;
  int lg  = bx & 7;
  int och = (bx >> 3) & 7;
  int tmp = bx >> 6;
  int tns = tmp % 3;
  int b   = tmp / 3;

  int tid = threadIdx.x;
  int wave = tid >> 6, lane = tid & 63, quad = lane >> 4, l16 = lane & 15;
  const u16* xg = xT + (size_t)b * NL * 64;

  // stage merged weights once (o-chunk slice, 3 d-slices)
  {
    const u16* wg = Wm + ((size_t)(tns * 3) * 512 + och * 64) * 64;
#pragma unroll
    for (int it = 0; it < 6; ++it) {
      int s = tid + it * 256;
      int d = s >> 9, r = s & 511;
      int o = r >> 3, c4 = r & 7;
      uint4 w = *(const uint4*)(wg + ((size_t)d * 512 + o) * 64 + c4 * 8);
      *(uint4*)&WS[d][o * LP + c4 * 8] = w;
    }
  }

  // XS prefetch helpers: 528 uint4 slots (66 rows x 8), <=3 per thread
  int xr0 = tid >> 3,          xc0 = (tid & 7) * 8;
  int xr1 = (tid + 256) >> 3,  xc1 = xc0;
  int xr2 = (tid + 512) >> 3,  xc2 = xc0;
  uint4 R0, R1, R2;
  uint4 Z = {0, 0, 0, 0};

#define LOAD_XS(tt)                                                         \
  {                                                                         \
    int base = (lg * 4 + (tt)) * 64 - 1;                                    \
    int g0 = base + xr0, g1 = base + xr1, g2 = base + xr2;                  \
    R0 = ((unsigned)g0 < NL) ? *(const uint4*)(xg + (size_t)g0 * 64 + xc0) : Z; \
    R1 = ((unsigned)g1 < NL) ? *(const uint4*)(xg + (size_t)g1 * 64 + xc1) : Z; \
    if (tid < 16)                                                           \
      R2 = ((unsigned)g2 < NL) ? *(const uint4*)(xg + (size_t)g2 * 64 + xc2) : Z; \
  }
#define STORE_XS(bf)                                                        \
  {                                                                         \
    *(uint4*)&XS[bf][xr0 * LP + xc0] = R0;                                  \
    *(uint4*)&XS[bf][xr1 * LP + xc1] = R1;                                  \
    if (tid < 16) *(uint4*)&XS[bf][xr2 * LP + xc2] = R2;                    \
  }

  LOAD_XS(0); STORE_XS(0);
  LOAD_XS(1);
  __syncthreads();

  // bias regs + v-path hoisted A fragments (tile-invariant)
  float bias4[4];
  bf16x8 aw[3][2];
  if (tns == 2) {
    const float* pbt = pbm + tns * 512 + och * 64 + wave * 16;
#pragma unroll
    for (int rr = 0; rr < 4; ++rr) bias4[rr] = pbt[quad * 4 + rr];
#pragma unroll
    for (int d = 0; d < 3; ++d)
#pragma unroll
      for (int kh = 0; kh < 2; ++kh)
        aw[d][kh] = ld_bf8(&WS[d][(wave * 16 + l16) * LP + kh * 32 + quad * 8]);
  } else {
    const float* pbt = pbm + tns * 512 + och * 64;
#pragma unroll
    for (int nt = 0; nt < 4; ++nt) bias4[nt] = pbt[nt * 16 + l16];
  }

  for (int t = 0; t < 4; ++t) {
    int cur = t & 1;
    f32x4 acc[4] = {{0,0,0,0},{0,0,0,0},{0,0,0,0},{0,0,0,0}};

    if (tns == 2) {
#pragma unroll
      for (int nt = 0; nt < 4; ++nt)
#pragma unroll
        for (int d = 0; d < 3; ++d)
#pragma unroll
          for (int kh = 0; kh < 2; ++kh) {
            bf16x8 bx8 = ld_bf8(&XS[cur][(nt * 16 + l16 + d) * LP + kh * 32 + quad * 8]);
            acc[nt] = __builtin_amdgcn_mfma_f32_16x16x32_bf16(aw[d][kh], bx8, acc[nt], 0, 0, 0);
          }
    } else {
      bf16x8 ax[3][2];
#pragma unroll
      for (int d = 0; d < 3; ++d)
#pragma unroll
        for (int kh = 0; kh < 2; ++kh)
          ax[d][kh] = ld_bf8(&XS[cur][(wave * 16 + l16 + d) * LP + kh * 32 + quad * 8]);
#pragma unroll
      for (int nt = 0; nt < 4; ++nt)
#pragma unroll
        for (int d = 0; d < 3; ++d)
#pragma unroll
          for (int kh = 0; kh < 2; ++kh) {
            bf16x8 bw = ld_bf8(&WS[d][(nt * 16 + l16) * LP + kh * 32 + quad * 8]);
            acc[nt] = __builtin_amdgcn_mfma_f32_16x16x32_bf16(ax[d][kh], bw, acc[nt], 0, 0, 0);
          }
    }

    if (t < 3) { STORE_XS((t + 1) & 1); if (t < 2) LOAD_XS(t + 2); }
    __syncthreads();   // XS[next] ready; OS needs no barrier (wave-private)

    // wave-private OS stripe: rows wave*16 .. wave*16+15
    if (tns == 2) {
      // rows = o, cols = l; bias by row
#pragma unroll
      for (int nt = 0; nt < 4; ++nt)
#pragma unroll
        for (int rr = 0; rr < 4; ++rr)
          OS[(wave * 16 + quad * 4 + rr) * LP + nt * 16 + l16] =
              f2bfu(acc[nt][rr] + bias4[rr]);
    } else {
      // rows = l, cols = o; bias by col
#pragma unroll
      for (int nt = 0; nt < 4; ++nt)
#pragma unroll
        for (int rr = 0; rr < 4; ++rr)
          OS[(wave * 16 + quad * 4 + rr) * LP + nt * 16 + l16] =
              f2bfu(acc[nt][rr] + bias4[nt]);
    }
    asm volatile("s_waitcnt lgkmcnt(0)" ::: "memory");  // own-wave writes landed

    // coalesced store: each wave stores its own 16 rows x 128B
    {
      int lt = lg * 4 + t;
      int rl = lane >> 2, ck = (lane & 3) * 16;
      int row = wave * 16 + rl;
      uint4 a = *(const uint4*)&OS[row * LP + ck];
      uint4 b2 = *(const uint4*)&OS[row * LP + ck + 8];
      u16* gp;
      if (tns == 2)
        gp = v + ((size_t)(b * HC + och * 64 + row)) * NL + lt * 64 + ck;
      else {
        u16* dst = (tns == 0) ? qT : kT;
        gp = dst + ((size_t)(b * 8 + och) * NL + lt * 64 + row) * 64 + ck;
      }
      *(uint4*)gp = a;
      *(uint4*)(gp + 8) = b2;
    }
  }
#undef LOAD_XS
#undef STORE_XS
}

// ---------------------------------------------------------------------------
// Kernel 2: flash attention + fused unify. 512 blocks = 32 bh * 16 q-tiles
// of 128. 8 waves * 16 queries each (512 threads) -> 4 waves/SIMD.
// K/V LDS double-buffered, ONE barrier per key-tile iteration. P and OT
// transposes fully in-register via permlane quad exchange. Q fragments
// straight from global. l-sum via ones-fragment MFMA (verified r4) --
// shifts the 14 VALU adds + 2 epilogue shuffles onto the idle MFMA pipe.
// This is the measured-best r2 structure (64.0 us). LDS 43.5 KB.
// ---------------------------------------------------------------------------
__global__ __launch_bounds__(512, 4) void attn_kernel(
    const u16* __restrict__ qT, const u16* __restrict__ kT,
    const u16* __restrict__ vg, const float* __restrict__ uw,
    float* __restrict__ outg)
{
  __shared__ __align__(16) u16 Kt[2][64 * LP];  // Kt[buf][key][c]
  __shared__ __align__(16) u16 Vt[2][64 * LP];  // Vt[buf][c][key]
  __shared__ __align__(16) u16 UW[64 * LP];     // UW[c][c']

  int bx = blockIdx.x;
  int qt = bx & 15, bh = bx >> 4;
  int b = bh >> 3, h = bh & 7;
  int tid = threadIdx.x;
  int wave = tid >> 6, lane = tid & 63, quad = lane >> 4, l16 = lane & 15;

  const u16* Qh = qT + (size_t)bh * NL * 64;
  const u16* Kh = kT + (size_t)bh * NL * 64;
  const u16* Vh = vg + ((size_t)(b * HC + h * NC)) * NL;
  int q0 = qt * 128;

  int sr = tid >> 3, ss = (tid & 7) * 8;    // K staging: row, u16-col (1 uint4/thread)
  int vc = tid >> 3, vk = (tid & 7) * 8;    // V staging: c row, key seg

  // stage UW head slice as bf16: UW[c][c'] = uw[c*512 + h*64 + c']
  {
    int c = tid >> 3, g = (tid & 7) * 8;
    const float4* s = (const float4*)(uw + (size_t)c * HC + h * 64 + g);
    float4 w0 = s[0], w1 = s[1];
    u16* d = &UW[c * LP + g];
    d[0] = f2bfu(w0.x); d[1] = f2bfu(w0.y); d[2] = f2bfu(w0.z); d[3] = f2bfu(w0.w);
    d[4] = f2bfu(w1.x); d[5] = f2bfu(w1.y); d[6] = f2bfu(w1.z); d[7] = f2bfu(w1.w);
  }

  // K/V tile loads (regs) + buf0 fill, tile1 prefetch (1 uint4 each/thread)
  uint4 ka, va;
  {
    ka = *(const uint4*)(Kh + (size_t)sr * 64 + ss);
    va = *(const uint4*)(Vh + (size_t)vc * NL + vk);
    *(uint4*)&Kt[0][sr * LP + ss] = ka;
    *(uint4*)&Vt[0][vc * LP + vk] = va;
    ka = *(const uint4*)(Kh + (size_t)(64 + sr) * 64 + ss);
    va = *(const uint4*)(Vh + (size_t)vc * NL + 64 + vk);
  }

  // Q fragments for this wave's 16 queries, straight from global (no LDS)
  bf16x8 bq[2];
#pragma unroll
  for (int kh = 0; kh < 2; ++kh)
    bq[kh] = ld_bf8(Qh + (size_t)(q0 + wave * 16 + l16) * 64 + kh * 32 + quad * 8);

  // all-ones A fragment for MFMA l-sum (column sums of P)
  bf16x8 ones = frag_from4(0x3F803F80u, 0x3F803F80u, 0x3F803F80u, 0x3F803F80u);

  __syncthreads();

  f32x4 o[4];
#pragma unroll
  for (int ct = 0; ct < 4; ++ct) o[ct] = (f32x4){0, 0, 0, 0};
  f32x4 lacc = {0, 0, 0, 0};

  for (int i = 0; i < 32; ++i) {
    int cur = i & 1;
    // K and V fragments (full 64-key tile per wave)
    bf16x8 ak[4][2], av[4][2];
#pragma unroll
    for (int j = 0; j < 4; ++j)
#pragma unroll
      for (int kh = 0; kh < 2; ++kh) {
        ak[j][kh] = ld_bf8(&Kt[cur][(j * 16 + l16) * LP + kh * 32 + quad * 8]);
        av[j][kh] = ld_bf8(&Vt[cur][(j * 16 + l16) * LP + kh * 32 + quad * 8]);
      }

    // S = K^T Q (rows=keys, cols=queries), log2 domain
    f32x4 s[4];
#pragma unroll
    for (int ktl = 0; ktl < 4; ++ktl) {
      f32x4 z = {0, 0, 0, 0};
      z = __builtin_amdgcn_mfma_f32_16x16x32_bf16(ak[ktl][0], bq[0], z, 0, 0, 0);
      z = __builtin_amdgcn_mfma_f32_16x16x32_bf16(ak[ktl][1], bq[1], z, 0, 0, 0);
      s[ktl] = z;
    }
    // p = 2^s; pack to bf16 pairs per ktl: w01=keys(+0,+1), w23=keys(+2,+3)
    u32 w01[4], w23[4];
#pragma unroll
    for (int ktl = 0; ktl < 4; ++ktl) {
      float p0 = EXP2F(s[ktl][0]);
      float p1 = EXP2F(s[ktl][1]);
      float p2 = EXP2F(s[ktl][2]);
      float p3 = EXP2F(s[ktl][3]);
      w01[ktl] = pk2(p0, p1);
      w23[ktl] = pk2(p2, p3);
    }
    // in-register transpose to PV B-fragments; O += V*P; l += colsum(P)
#pragma unroll
    for (int kh = 0; kh < 2; ++kh) {
      u32 F0, F1, F2, F3;
      XCHG(w01[2 * kh], w01[2 * kh + 1], F0, F2);
      XCHG(w23[2 * kh], w23[2 * kh + 1], F1, F3);
      bf16x8 bp = frag_from4(F0, F1, F2, F3);
      lacc = __builtin_amdgcn_mfma_f32_16x16x32_bf16(ones, bp, lacc, 0, 0, 0);
#pragma unroll
      for (int ct = 0; ct < 4; ++ct)
        o[ct] = __builtin_amdgcn_mfma_f32_16x16x32_bf16(av[ct][kh], bp, o[ct], 0, 0, 0);
    }

    if (i < 31) {
      int nxt = cur ^ 1;
      *(uint4*)&Kt[nxt][sr * LP + ss] = ka;
      *(uint4*)&Vt[nxt][vc * LP + vk] = va;
      if (i < 30) {
        int kt2 = (i + 2) * 64;
        ka = *(const uint4*)(Kh + (size_t)(kt2 + sr) * 64 + ss);
        va = *(const uint4*)(Vh + (size_t)vc * NL + kt2 + vk);
      }
    }
    __syncthreads();   // the ONLY barrier per iteration
  }

  // epilogue: lacc[0] = l for query l16 (ones-MFMA, rows all equal)
  float* ob = outg + ((size_t)b * NC) * NL;
  {
    float rinv = 1.0f / lacc[0];

    // pack normalized O (rows=c', cols=q) then quad-exchange to B-fragments
    u32 w01[4], w23[4];
#pragma unroll
    for (int ct = 0; ct < 4; ++ct) {
      w01[ct] = pk2(o[ct][0] * rinv, o[ct][1] * rinv);
      w23[ct] = pk2(o[ct][2] * rinv, o[ct][3] * rinv);
    }
    bf16x8 ot[2];
#pragma unroll
    for (int kh = 0; kh < 2; ++kh) {
      u32 F0, F1, F2, F3;
      XCHG(w01[2 * kh], w01[2 * kh + 1], F0, F2);
      XCHG(w23[2 * kh], w23[2 * kh + 1], F1, F3);
      ot[kh] = frag_from4(F0, F1, F2, F3);
    }

    int qcol = q0 + wave * 16 + l16;
#pragma unroll
    for (int mt = 0; mt < 4; ++mt) {
      f32x4 acc = {0, 0, 0, 0};
#pragma unroll
      for (int kh = 0; kh < 2; ++kh) {
        bf16x8 a = ld_bf8(&UW[(mt * 16 + l16) * LP + kh * 32 + quad * 8]);
        acc = __builtin_amdgcn_mfma_f32_16x16x32_bf16(a, ot[kh], acc, 0, 0, 0);
      }
#pragma unroll
      for (int rr = 0; rr < 4; ++rr) {
        int c = mt * 16 + quad * 4 + rr;
        atomicAdd(&ob[(size_t)c * NL + qcol], acc[rr]);
      }
    }
  }
}

// ---------------------------------------------------------------------------
extern "C" void kernel_launch(void* const* d_in, const int* in_sizes, int n_in,
                              void* d_out, int out_size, void* d_ws, size_t ws_size,
                              hipStream_t stream) {
  (void)in_sizes; (void)n_in; (void)out_size; (void)ws_size;
  const float* x   = (const float*)d_in[0];
  const float* qdw = (const float*)d_in[1];
  const float* qdb = (const float*)d_in[2];
  const float* qpw = (const float*)d_in[3];
  const float* qpb = (const float*)d_in[4];
  const float* kdw = (const float*)d_in[5];
  const float* kdb = (const float*)d_in[6];
  const float* kpw = (const float*)d_in[7];
  const float* kpb = (const float*)d_in[8];
  const float* vdw = (const float*)d_in[9];
  const float* vdb = (const float*)d_in[10];
  const float* vpw = (const float*)d_in[11];
  const float* vpb = (const float*)d_in[12];
  const float* uw  = (const float*)d_in[13];
  const float* ub  = (const float*)d_in[14];

  char* ws = (char*)d_ws;
  u16*   xT  = (u16*)(ws + XT_OFF);
  u16*   Wm  = (u16*)(ws + WM_OFF);
  float* pbm = (float*)(ws + PBM_OFF);
  u16*   v   = (u16*)(ws + V_OFF);
  u16*   qT  = (u16*)(ws + QT_OFF);
  u16*   kT  = (u16*)(ws + KT_OFF);
  float* out = (float*)d_out;

  prep_all<<<1030, 256, 0, stream>>>(
      x, qdw, qdb, qpw, qpb, kdw, kdb, kpw, kpb, vdw, vdb, vpw, vpb,
      ub, Wm, pbm, xT, out);
  qkv_gemm<<<768, 256, 0, stream>>>(xT, Wm, pbm, v, qT, kT);
  attn_kernel<<<512, 512, 0, stream>>>(qT, kT, v, uw, out);
}